// Round 11
// baseline (1083.704 us; speedup 1.0000x reference)
//
#include <hip/hip_runtime.h>

typedef unsigned short u16;
typedef __bf16 bf16x8 __attribute__((ext_vector_type(8)));
typedef float f32x4 __attribute__((ext_vector_type(4)));

#define BATCH 32768L

__device__ __forceinline__ u16 f2b(float f) {
  union { float f; unsigned int u; } v; v.f = f;
  unsigned int r = v.u + 0x7fffu + ((v.u >> 16) & 1u);
  return (u16)(r >> 16);
}
__device__ __forceinline__ float b2f(u16 h) {
  union { unsigned int u; float f; } v; v.u = ((unsigned int)h) << 16;
  return v.f;
}
// divide-free gate math: v_exp_f32 (exp2) + v_rcp_f32
__device__ __forceinline__ float rcpf(float x) { return __builtin_amdgcn_rcpf(x); }
__device__ __forceinline__ float sigf(float x) {
  return rcpf(1.f + __builtin_amdgcn_exp2f(-1.442695041f * x));
}
__device__ __forceinline__ float tanh_f(float x) {
  return 1.f - 2.f * rcpf(1.f + __builtin_amdgcn_exp2f(2.885390082f * x));
}

// async global -> LDS, 16B per lane; LDS dest is wave-uniform base + lane*16
__device__ __forceinline__ void gload16(const void* g, void* l) {
  __builtin_amdgcn_global_load_lds((const __attribute__((address_space(1))) unsigned int*)g,
                                   (__attribute__((address_space(3))) unsigned int*)l,
                                   16, 0, 0);
}

// ---------------- fused prep: 9 weight cvts (f32->bf16, padded) + 3 bias sums ----------------
struct PrepP {
  const float* s[9]; u16* d[9]; int sc[9]; int dc[9]; long n[9];
  const float* ba[3]; const float* bb_[3]; float* bo[3];
};

__global__ void prep_kernel(PrepP p, long cvtTotal, long total) {
  for (long i = (long)blockIdx.x * blockDim.x + threadIdx.x; i < total;
       i += (long)gridDim.x * blockDim.x) {
    if (i < cvtTotal) {
      long off = i; int sg = 0;
      while (off >= p.n[sg]) { off -= p.n[sg]; ++sg; }
      long r = off / p.dc[sg]; int c = (int)(off - r * p.dc[sg]);
      p.d[sg][off] = (c < p.sc[sg]) ? f2b(p.s[sg][r * (long)p.sc[sg] + c]) : (u16)0;
    } else {
      long j = i - cvtTotal; int sg = (int)(j >> 10); int k = (int)(j & 1023);
      p.bo[sg][k] = p.ba[sg][k] + p.bb_[sg][k];
    }
  }
}

// ---------------- MFMA GEMM: C = act(A1@W1^T + A2@W2^T + bias) ----------------
// Block: 64 rows x (NG x 64) cols, 4 waves. Wave w: all 64 rows x its own
// 16-col subfrag of every 64-col group g. acc[4][NG].
// A: LDS-staged (4x intra-block reuse), gload16, 2-buf, slot-swizzled
// (conflict-free, verified 0 in r9), one __syncthreads per 32-K chunk.
// B: DIRECT global->VGPR, register double-buffered (bcur/bnext). Per-wave
// B-frag loads are 64B-coalesced (lanes 0-15 = 16 consecutive W rows) and
// L2-hot; per-block L2 traffic identical to LDS staging, but removes 4 of 8
// ds_reads + 4 of 5 staging instrs per wave-chunk and decouples B from the
// barrier. LDS total = 8KB.
// Slot swizzle for A: 16B unit u of row r stored at slot (u+(r>>1))&3;
// writes HW-linear so per-lane GLOBAL source unit = ((l&3)-(l>>3))&3;
// reads slot ((l>>4)+((l&15)>>1))&3.
// REMAP=1 (cells): 1D grid nb*4 (nb%8==0); 4 blocks sharing an A-slab get
// ids differing by 8 -> same XCD -> A staged from L2 after first touch.
// EPI=0: store bf16 (+bias via acc-init, optional relu). EPI=1 (NG=4): LSTM.
template <int EPI, int NG, int REMAP>
__global__ __launch_bounds__(256, 3)
void mfma_gemm9(const u16* __restrict__ A1, long lda1, int K1,
                const u16* __restrict__ W1, int wld1,
                const u16* __restrict__ A2, long lda2, int K2,
                const u16* __restrict__ W2, int wld2,
                int gs, int ys, const float* __restrict__ bias,
                u16* __restrict__ out0, int ldo, int relu,
                const float* __restrict__ cprev, float* __restrict__ cout,
                u16* __restrict__ hout, int ldh)
{
  __shared__ u16 As[2][64 * 32];           // [row][4 slots x 16B], slot-swizzled
  const int tid = threadIdx.x;
  const int l = tid & 63, w = tid >> 6;

  int row_blk, yb;
  if constexpr (REMAP) {
    const int vid = blockIdx.x;
    row_blk = (vid >> 5) * 8 + (vid & 7);
    yb = (vid >> 3) & 3;
  } else {
    row_blk = blockIdx.x;
    yb = blockIdx.y;
  }
  const long bm = (long)row_blk * 64;

  const int nch1 = K1 >> 5;
  const int nch2 = A2 ? (K2 >> 5) : 0;
  const int nt = nch1 + nch2;

  const int colb = l & 15, rq = l >> 4;

  // bias -> acc init (MFMA C-in)
  f32x4 acc[4][NG];
  {
    float bw[NG];
#pragma unroll
    for (int g = 0; g < NG; ++g) bw[g] = bias[g * gs + yb * ys + w * 16 + colb];
#pragma unroll
    for (int rf = 0; rf < 4; ++rf)
#pragma unroll
      for (int g = 0; g < NG; ++g) acc[rf][g] = (f32x4){bw[g], bw[g], bw[g], bw[g]};
  }

  const int l4q = l >> 2;                                  // row within 16-row slab
  const int swzs = (((l & 3) - (l >> 3)) & 3) * 16;        // pre-swizzled source offset (A)

  const char* pA;
  const char* pB[NG];
  auto initA = [&](const u16* A, long lda) {
    pA = (const char*)A + ((bm + w * 16 + l4q) * lda) * 2 + swzs;
  };
  // direct-B: lane l loads W[wrow = g*gs + yb*ys + w*16 + (l&15)][kb + (l>>4)*8 ..+8]
  auto initB = [&](const u16* W, int wld) {
#pragma unroll
    for (int g = 0; g < NG; ++g) {
      const long wrow = (long)g * gs + (long)yb * ys + w * 16 + (l & 15);
      pB[g] = (const char*)W + (wrow * (long)wld + (l >> 4) * 8) * 2;
    }
  };
  auto stageA = [&](int buf) {
    gload16(pA, &As[buf][(w * 16) * 32]);
    pA += 64;
  };

  initA(A1, lda1);
  initB(W1, wld1);
  stageA(0);
  bf16x8 bcur[NG];
#pragma unroll
  for (int g = 0; g < NG; ++g) {
    bcur[g] = *(const bf16x8*)pB[g];
    pB[g] += 64;
  }

  const int rb = l & 15;
  const int koff = ((((l >> 4) + ((l & 15) >> 1)) & 3) * 8);   // slot-swizzled A read offset
  int cur = 0;
  for (int ch = 0; ch < nt; ++ch) {
    __syncthreads();                       // As[cur] staged; prior reads drained
    const bool haveNext = (ch + 1 < nt);
    if (haveNext) {
      if (A2 && ch + 1 == nch1) initA(A2, lda2);
      stageA(cur ^ 1);
    }
    bf16x8 bnext[NG];
    if (haveNext) {
      if (A2 && ch + 1 == nch1) initB(W2, wld2);
#pragma unroll
      for (int g = 0; g < NG; ++g) {
        bnext[g] = *(const bf16x8*)pB[g];
        pB[g] += 64;
      }
    }
    const u16* Ab = As[cur];
    bf16x8 af[4];
#pragma unroll
    for (int rf = 0; rf < 4; ++rf)
      af[rf] = *(const bf16x8*)&Ab[(rf * 16 + rb) * 32 + koff];
#pragma unroll
    for (int g = 0; g < NG; ++g) {
#pragma unroll
      for (int rf = 0; rf < 4; ++rf)
        acc[rf][g] = __builtin_amdgcn_mfma_f32_16x16x32_bf16(af[rf], bcur[g], acc[rf][g], 0, 0, 0);
    }
    if (haveNext) {
#pragma unroll
      for (int g = 0; g < NG; ++g) bcur[g] = bnext[g];
    }
    cur ^= 1;
  }

  if constexpr (EPI == 0) {
#pragma unroll
    for (int g = 0; g < NG; ++g) {
      const int wrow = g * gs + yb * ys + w * 16 + colb;
#pragma unroll
      for (int rf = 0; rf < 4; ++rf) {
#pragma unroll
        for (int r = 0; r < 4; ++r) {
          float vv = acc[rf][g][r];
          if (relu) vv = fmaxf(vv, 0.f);
          out0[(bm + rf * 16 + rq * 4 + r) * (long)ldo + wrow] = f2b(vv);
        }
      }
    }
  } else {
    const int cb = yb * ys + w * 16 + colb;
#pragma unroll
    for (int rf = 0; rf < 4; ++rf) {
#pragma unroll
      for (int r = 0; r < 4; ++r) {
        const long row = bm + rf * 16 + rq * 4 + r;
        const float zi = acc[rf][0][r];
        const float zf = acc[rf][1][r];
        const float zg = acc[rf][2][r];
        const float zo = acc[rf][3][r];
        const float cp = cprev ? cprev[row * 256 + cb] : 0.f;
        const float cn = sigf(zf) * cp + sigf(zi) * tanh_f(zg);
        const float hn = sigf(zo) * tanh_f(cn);
        cout[row * 256 + cb] = cn;
        hout[row * (long)ldh + cb] = f2b(hn);
      }
    }
  }
}

// ---------------- fused front: baseline MLP+LN, last_cbc, zpad, xbf cvt ----------------
__global__ __launch_bounds__(256)
void front_kernel(const float* __restrict__ cbc, const float* __restrict__ baseline,
                  const float* __restrict__ Wb, const float* __restrict__ bb,
                  const float* __restrict__ ln_g, const float* __restrict__ ln_b,
                  u16* __restrict__ dec_in, u16* __restrict__ xbf)
{
  __shared__ float wbs[1280];
  __shared__ float bbs[128], lgs[128], lbs[128];
  const int tid = threadIdx.x;
  for (int i = tid; i < 1280; i += 256) wbs[i] = Wb[i];
  if (tid < 128) { bbs[tid] = bb[tid]; lgs[tid] = ln_g[tid]; lbs[tid] = ln_b[tid]; }
  __syncthreads();
  const int l = tid & 63, w = tid >> 6;
  const long row = (long)blockIdx.x * 4 + w;
#pragma unroll
  for (int e = l; e < 96; e += 64) {
    const int t = e >> 5, c = e & 31;
    xbf[(row * 3 + t) * 32 + c] = (c < 6) ? f2b(cbc[row * 18 + t * 6 + c]) : (u16)0;
  }
  if (l < 6) dec_in[row * 416 + l] = f2b(cbc[row * 18 + 12 + l]);
  else if (l < 32) dec_in[row * 416 + 390 + (l - 6)] = 0;
  float bl[10];
#pragma unroll
  for (int k = 0; k < 10; ++k) bl[k] = baseline[row * 10 + k];
  const int c0 = l, c1 = l + 64;
  float z0 = bbs[c0], z1 = bbs[c1];
#pragma unroll
  for (int k = 0; k < 10; ++k) { z0 += bl[k] * wbs[c0 * 10 + k]; z1 += bl[k] * wbs[c1 * 10 + k]; }
  z0 = fmaxf(z0, 0.f); z1 = fmaxf(z1, 0.f);
  float s = z0 + z1, sq = z0 * z0 + z1 * z1;
#pragma unroll
  for (int m = 32; m; m >>= 1) { s += __shfl_xor(s, m); sq += __shfl_xor(sq, m); }
  const float mu = s * (1.f / 128.f);
  const float var = sq * (1.f / 128.f) - mu * mu;
  const float rs = rsqrtf(var + 1e-5f);
  dec_in[row * 416 + 262 + c0] = f2b((z0 - mu) * rs * lgs[c0] + lbs[c0]);
  dec_in[row * 416 + 262 + c1] = f2b((z1 - mu) * rs * lgs[c1] + lbs[c1]);
}

// ---------------- attention: scores -> softmax(3) -> context -> dec_in[:, 6:262] ----------------
__global__ __launch_bounds__(256)
void attn_kernel(const u16* __restrict__ q, const u16* __restrict__ ep,
                 const u16* __restrict__ eo, const float* __restrict__ va,
                 const float* __restrict__ ba, u16* __restrict__ dec_in)
{
  const int tid = threadIdx.x;
  const int l = tid & 63, w = tid >> 6;
  const long row = (long)blockIdx.x * 4 + w;
  const int c = l * 4;
  float qv[4], vav[4];
  {
    ushort4 qu = *(const ushort4*)&q[row * 256 + c];
    qv[0] = b2f(qu.x); qv[1] = b2f(qu.y); qv[2] = b2f(qu.z); qv[3] = b2f(qu.w);
    float4 vv = *(const float4*)&va[c];
    vav[0] = vv.x; vav[1] = vv.y; vav[2] = vv.z; vav[3] = vv.w;
  }
  float s[3];
#pragma unroll
  for (int t = 0; t < 3; ++t) {
    ushort4 eu = *(const ushort4*)&ep[row * 768 + t * 256 + c];
    float p = tanh_f(qv[0] + b2f(eu.x)) * vav[0]
            + tanh_f(qv[1] + b2f(eu.y)) * vav[1]
            + tanh_f(qv[2] + b2f(eu.z)) * vav[2]
            + tanh_f(qv[3] + b2f(eu.w)) * vav[3];
#pragma unroll
    for (int m = 32; m; m >>= 1) p += __shfl_xor(p, m);
    s[t] = p + ba[0];
  }
  const float mx = fmaxf(s[0], fmaxf(s[1], s[2]));
  const float e0 = __expf(s[0] - mx), e1 = __expf(s[1] - mx), e2 = __expf(s[2] - mx);
  const float inv = rcpf(e0 + e1 + e2);
  const float w0 = e0 * inv, w1 = e1 * inv, w2 = e2 * inv;
  const ushort4 a0 = *(const ushort4*)&eo[row * 768 + 0 * 256 + c];
  const ushort4 a1 = *(const ushort4*)&eo[row * 768 + 1 * 256 + c];
  const ushort4 a2 = *(const ushort4*)&eo[row * 768 + 2 * 256 + c];
  u16* dp = &dec_in[row * 416 + 6 + c];
  dp[0] = f2b(w0 * b2f(a0.x) + w1 * b2f(a1.x) + w2 * b2f(a2.x));
  dp[1] = f2b(w0 * b2f(a0.y) + w1 * b2f(a1.y) + w2 * b2f(a2.y));
  dp[2] = f2b(w0 * b2f(a0.z) + w1 * b2f(a1.z) + w2 * b2f(a2.z));
  dp[3] = f2b(w0 * b2f(a0.w) + w1 * b2f(a1.w) + w2 * b2f(a2.w));
}

// ---------------- output head tail: delta = t1 @ Wo2^T + bo2; pred = last + delta ----------------
__global__ __launch_bounds__(256)
void delta_kernel(const u16* __restrict__ t1, const float* __restrict__ Wo2,
                  const float* __restrict__ bo2, const float* __restrict__ lastp, int lstride,
                  float* __restrict__ outp, int ostride, u16* __restrict__ dec_in)
{
  __shared__ float w2s[768];
  __shared__ float part[64][4][6];
  const int tid = threadIdx.x;
  for (int i = tid; i < 768; i += 256) w2s[i] = Wo2[i];
  __syncthreads();
  const int rw = tid >> 2, q = tid & 3;
  const long row = (long)blockIdx.x * 64 + rw;
  float p[6] = {0.f, 0.f, 0.f, 0.f, 0.f, 0.f};
  const u16* tp = &t1[row * 128 + q * 32];
#pragma unroll
  for (int it = 0; it < 4; ++it) {
    int4 chunk = *(const int4*)&tp[it * 8];
    const u16* cu = (const u16*)&chunk;
#pragma unroll
    for (int e = 0; e < 8; ++e) {
      const float tv = b2f(cu[e]);
      const int k = q * 32 + it * 8 + e;
#pragma unroll
      for (int j = 0; j < 6; ++j) p[j] += tv * w2s[j * 128 + k];
    }
  }
#pragma unroll
  for (int j = 0; j < 6; ++j) part[rw][q][j] = p[j];
  __syncthreads();
  if (tid < 64) {
    const long r2 = (long)blockIdx.x * 64 + tid;
#pragma unroll
    for (int j = 0; j < 6; ++j) {
      const float d = bo2[j] + part[tid][0][j] + part[tid][1][j] + part[tid][2][j] + part[tid][3][j];
      const float pr = lastp[r2 * lstride + j] + d;
      outp[r2 * ostride + j] = pr;
      dec_in[r2 * 416 + j] = f2b(pr);
    }
  }
}

extern "C" void kernel_launch(void* const* d_in, const int* in_sizes, int n_in,
                              void* d_out, int out_size, void* d_ws, size_t ws_size,
                              hipStream_t stream) {
  const float* cbc   = (const float*)d_in[0];
  const float* base  = (const float*)d_in[1];
  const float* W_ih0 = (const float*)d_in[2];
  const float* W_hh0 = (const float*)d_in[3];
  const float* b_ih0 = (const float*)d_in[4];
  const float* b_hh0 = (const float*)d_in[5];
  const float* W_ih1 = (const float*)d_in[6];
  const float* W_hh1 = (const float*)d_in[7];
  const float* b_ih1 = (const float*)d_in[8];
  const float* b_hh1 = (const float*)d_in[9];
  const float* Wb    = (const float*)d_in[10];
  const float* bb    = (const float*)d_in[11];
  const float* ln_g  = (const float*)d_in[12];
  const float* ln_b  = (const float*)d_in[13];
  const float* W1a   = (const float*)d_in[14];
  const float* b1a   = (const float*)d_in[15];
  const float* W2a   = (const float*)d_in[16];
  const float* b2a   = (const float*)d_in[17];
  const float* va    = (const float*)d_in[18];
  const float* ba    = (const float*)d_in[19];
  const float* Wd_ih = (const float*)d_in[20];
  const float* Wd_hh = (const float*)d_in[21];
  const float* bd_ih = (const float*)d_in[22];
  const float* bd_hh = (const float*)d_in[23];
  const float* Wo1   = (const float*)d_in[24];
  const float* bo1   = (const float*)d_in[25];
  const float* Wo2   = (const float*)d_in[26];
  const float* bo2   = (const float*)d_in[27];
  float* out = (float*)d_out;
  (void)in_sizes; (void)n_in; (void)out_size;

  unsigned char* wsb = (unsigned char*)d_ws;
  size_t off = 0;
  auto alloc = [&](size_t bytes) -> void* {
    void* p = wsb + off;
    off += (bytes + 255) & ~(size_t)255;
    return p;
  };
  // ---- persistent (weights, biases) ----
  u16* wih0b = (u16*)alloc(1024 * 32 * 2);    // padded K 6->32
  u16* whh0b = (u16*)alloc(1024 * 256 * 2);
  u16* wih1b = (u16*)alloc(1024 * 256 * 2);
  u16* whh1b = (u16*)alloc(1024 * 256 * 2);
  u16* wdihb = (u16*)alloc(1024 * 416 * 2);   // padded K 390->416
  u16* wdhhb = (u16*)alloc(1024 * 256 * 2);
  u16* w1ab  = (u16*)alloc(256 * 256 * 2);
  u16* w2ab  = (u16*)alloc(256 * 256 * 2);
  u16* wo1b  = (u16*)alloc(128 * 256 * 2);
  float* bsum0 = (float*)alloc(1024 * 4);
  float* bsum1 = (float*)alloc(1024 * 4);
  float* bsumd = (float*)alloc(1024 * 4);

  // ---- batch chunking: per-row bytes; R multiple of 512 (XCD remap needs nb%8==0) ----
  const long perRow = 6656;
  long avail = (long)ws_size - (long)off - 32768;
  long R = avail > 0 ? avail / perRow : 512;
  R &= ~511L;
  if (R > BATCH) R = BATCH;
  if (R < 512) R = 512;

  u16* xbf    = (u16*)alloc((size_t)R * 96 * 2);    // [R*3][32] padded
  u16* y0     = (u16*)alloc((size_t)R * 768 * 2);   // layer0 outputs; later enc_proj
  u16* y1     = (u16*)alloc((size_t)R * 768 * 2);   // layer1 outputs = encoder_outputs
  float* cbuf = (float*)alloc((size_t)R * 256 * 4); // c row-major [row][256]
  u16* hdec0  = (u16*)alloc((size_t)R * 256 * 2);
  u16* hdec1  = (u16*)alloc((size_t)R * 256 * 2);
  u16* qt1    = (u16*)alloc((size_t)R * 256 * 2);   // q then t1
  u16* dec_in = (u16*)alloc((size_t)R * 416 * 2);   // [R][416], cols 390..415 zero

  // ---- fused prep (single launch) ----
  {
    PrepP p;
    const float* ss[9] = {W_ih0, W_hh0, W_ih1, W_hh1, Wd_ih, Wd_hh, W1a, W2a, Wo1};
    u16* dd[9]         = {wih0b, whh0b, wih1b, whh1b, wdihb, wdhhb, w1ab, w2ab, wo1b};
    int scv[9]         = {6, 256, 256, 256, 390, 256, 256, 256, 256};
    int dcv[9]         = {32, 256, 256, 256, 416, 256, 256, 256, 256};
    long rows[9]       = {1024, 1024, 1024, 1024, 1024, 1024, 256, 256, 128};
    long cvtTotal = 0;
    for (int i = 0; i < 9; ++i) {
      p.s[i] = ss[i]; p.d[i] = dd[i]; p.sc[i] = scv[i]; p.dc[i] = dcv[i];
      p.n[i] = rows[i] * dcv[i]; cvtTotal += p.n[i];
    }
    p.ba[0] = b_ih0; p.bb_[0] = b_hh0; p.bo[0] = bsum0;
    p.ba[1] = b_ih1; p.bb_[1] = b_hh1; p.bo[1] = bsum1;
    p.ba[2] = bd_ih; p.bb_[2] = bd_hh; p.bo[2] = bsumd;
    prep_kernel<<<dim3(2048), dim3(256), 0, stream>>>(p, cvtTotal, cvtTotal + 3072);
  }

  const dim3 blk(256);

  for (long r0 = 0; r0 < BATCH; r0 += R) {
    const long Rc = (BATCH - r0 < R) ? (BATCH - r0) : R;
    const unsigned nb = (unsigned)(Rc / 64);
    const dim3 gcell(nb * 4);                 // 1D, XCD-remapped in-kernel
    const float* cbc_c  = cbc + r0 * 18;
    const float* base_c = base + r0 * 10;
    float* out_c = out + r0 * 30;

    front_kernel<<<dim3((unsigned)(Rc / 4)), blk, 0, stream>>>(
        cbc_c, base_c, Wb, bb, ln_g, ln_b, dec_in, xbf);

    // ---- encoder layer 0 (K1 padded to 32) ----
    for (int t = 0; t < 3; ++t) {
      const u16* a2 = t ? (y0 + (t - 1) * 256) : nullptr;
      mfma_gemm9<1, 4, 1><<<gcell, blk, 0, stream>>>(
          xbf + t * 32, 96, 32, wih0b, 32,
          a2, 768, 256, whh0b, 256,
          256, 64, bsum0,
          nullptr, 0, 0,
          (t ? cbuf : nullptr), cbuf, y0 + t * 256, 768);
    }
    // ---- encoder layer 1 ----
    for (int t = 0; t < 3; ++t) {
      const u16* a2 = t ? (y1 + (t - 1) * 256) : nullptr;
      mfma_gemm9<1, 4, 1><<<gcell, blk, 0, stream>>>(
          y0 + t * 256, 768, 256, wih1b, 256,
          a2, 768, 256, whh1b, 256,
          256, 64, bsum1,
          nullptr, 0, 0,
          (t ? cbuf : nullptr), cbuf, y1 + t * 256, 768);
    }
    // ---- enc_proj = encoder_outputs @ W2a^T + b2a (into y0, now dead) ----
    mfma_gemm9<0, 4, 0><<<dim3(nb * 3, 1), blk, 0, stream>>>(
        y1, 256, 256, w2ab, 256,
        nullptr, 0, 0, nullptr, 0,
        64, 0, b2a,
        y0, 256, 0,
        nullptr, nullptr, nullptr, 0);

    // ---- decoder ----
    const u16* hcur = y1 + 2 * 256; long hld = 768;   // hT
    for (int s = 0; s < 5; ++s) {
      // q = h @ W1a^T + b1a
      mfma_gemm9<0, 4, 0><<<dim3(nb, 1), blk, 0, stream>>>(
          hcur, hld, 256, w1ab, 256,
          nullptr, 0, 0, nullptr, 0,
          64, 0, b1a,
          qt1, 256, 0,
          nullptr, nullptr, nullptr, 0);
      // attention -> context into dec_in[:, 6:262]
      attn_kernel<<<dim3((unsigned)(Rc / 4)), blk, 0, stream>>>(qt1, y0, y1, va, ba, dec_in);
      // decoder LSTM cell (K1 padded to 416)
      u16* hnext = (s & 1) ? hdec1 : hdec0;
      mfma_gemm9<1, 4, 1><<<gcell, blk, 0, stream>>>(
          dec_in, 416, 416, wdihb, 416,
          hcur, hld, 256, wdhhb, 256,
          256, 64, bsumd,
          nullptr, 0, 0,
          cbuf, cbuf, hnext, 256);
      hcur = hnext; hld = 256;
      // t1 = relu(h @ Wo1^T + bo1)
      mfma_gemm9<0, 2, 0><<<dim3(nb, 1), blk, 0, stream>>>(
          hcur, 256, 256, wo1b, 256,
          nullptr, 0, 0, nullptr, 0,
          64, 0, bo1,
          qt1, 128, 1,
          nullptr, nullptr, nullptr, 0);
      // delta + pred
      const float* lastp = (s == 0) ? (cbc_c + 12) : (out_c + (long)(s - 1) * 6);
      const int lstr = (s == 0) ? 18 : 30;
      delta_kernel<<<dim3((unsigned)(Rc / 64)), blk, 0, stream>>>(
          qt1, Wo2, bo2, lastp, lstr, out_c + (long)s * 6, 30, dec_in);
    }
  }
}

// Round 12
// 881.635 us; speedup vs baseline: 1.2292x; 1.2292x over previous
//
#include <hip/hip_runtime.h>

typedef unsigned short u16;
typedef __bf16 bf16x8 __attribute__((ext_vector_type(8)));
typedef float f32x4 __attribute__((ext_vector_type(4)));

#define BATCH 32768L

__device__ __forceinline__ u16 f2b(float f) {
  union { float f; unsigned int u; } v; v.f = f;
  unsigned int r = v.u + 0x7fffu + ((v.u >> 16) & 1u);
  return (u16)(r >> 16);
}
__device__ __forceinline__ float b2f(u16 h) {
  union { unsigned int u; float f; } v; v.u = ((unsigned int)h) << 16;
  return v.f;
}
// divide-free gate math: v_exp_f32 (exp2) + v_rcp_f32
__device__ __forceinline__ float rcpf(float x) { return __builtin_amdgcn_rcpf(x); }
__device__ __forceinline__ float sigf(float x) {
  return rcpf(1.f + __builtin_amdgcn_exp2f(-1.442695041f * x));
}
__device__ __forceinline__ float tanh_f(float x) {
  return 1.f - 2.f * rcpf(1.f + __builtin_amdgcn_exp2f(2.885390082f * x));
}

// async global -> LDS, 16B per lane; LDS dest is wave-uniform base + lane*16
__device__ __forceinline__ void gload16(const void* g, void* l) {
  __builtin_amdgcn_global_load_lds((const __attribute__((address_space(1))) unsigned int*)g,
                                   (__attribute__((address_space(3))) unsigned int*)l,
                                   16, 0, 0);
}

// ---------------- fused prep: 9 weight cvts (f32->bf16, padded) + 3 bias sums ----------------
struct PrepP {
  const float* s[9]; u16* d[9]; int sc[9]; int dc[9]; long n[9];
  const float* ba[3]; const float* bb_[3]; float* bo[3];
};

__global__ void prep_kernel(PrepP p, long cvtTotal, long total) {
  for (long i = (long)blockIdx.x * blockDim.x + threadIdx.x; i < total;
       i += (long)gridDim.x * blockDim.x) {
    if (i < cvtTotal) {
      long off = i; int sg = 0;
      while (off >= p.n[sg]) { off -= p.n[sg]; ++sg; }
      long r = off / p.dc[sg]; int c = (int)(off - r * p.dc[sg]);
      p.d[sg][off] = (c < p.sc[sg]) ? f2b(p.s[sg][r * (long)p.sc[sg] + c]) : (u16)0;
    } else {
      long j = i - cvtTotal; int sg = (int)(j >> 10); int k = (int)(j & 1023);
      p.bo[sg][k] = p.ba[sg][k] + p.bb_[sg][k];
    }
  }
}

// ---------------- MFMA GEMM: C = act(A1@W1^T + A2@W2^T + bias) ----------------
// r9 configuration exactly (best measured: 82.8us dec cell, 0 bank conflicts):
// 64 rows x (NG x 64) cols, 4 waves, 2-buf LDS via global_load_lds, one
// __syncthreads per 32-K chunk, slot swizzle, XCD REMAP for cells.
// MINW: launch_bounds min-waves/EU (cells: 4 -> 4 blocks/CU by LDS+VGPR).
template <int EPI, int NG, int REMAP, int MINW>
__global__ __launch_bounds__(256, MINW)
void mfma_gemm7(const u16* __restrict__ A1, long lda1, int K1,
                const u16* __restrict__ W1, int wld1,
                const u16* __restrict__ A2, long lda2, int K2,
                const u16* __restrict__ W2, int wld2,
                int gs, int ys, const float* __restrict__ bias,
                u16* __restrict__ out0, int ldo, int relu,
                const float* __restrict__ cprev, float* __restrict__ cout,
                u16* __restrict__ hout, int ldh)
{
  __shared__ u16 As[2][64 * 32];           // [row][4 slots x 16B], slot-swizzled
  __shared__ u16 Bs[2][NG * 64 * 32];
  const int tid = threadIdx.x;
  const int l = tid & 63, w = tid >> 6;

  int row_blk, yb;
  if constexpr (REMAP) {
    const int vid = blockIdx.x;
    row_blk = (vid >> 5) * 8 + (vid & 7);
    yb = (vid >> 3) & 3;
  } else {
    row_blk = blockIdx.x;
    yb = blockIdx.y;
  }
  const long bm = (long)row_blk * 64;

  const int nch1 = K1 >> 5;
  const int nch2 = A2 ? (K2 >> 5) : 0;
  const int nt = nch1 + nch2;

  const int colb = l & 15, rq = l >> 4;

  // bias -> acc init (MFMA C-in)
  f32x4 acc[4][NG];
  {
    float bw[NG];
#pragma unroll
    for (int g = 0; g < NG; ++g) bw[g] = bias[g * gs + yb * ys + w * 16 + colb];
#pragma unroll
    for (int rf = 0; rf < 4; ++rf)
#pragma unroll
      for (int g = 0; g < NG; ++g) acc[rf][g] = (f32x4){bw[g], bw[g], bw[g], bw[g]};
  }

  const int l4q = l >> 2;                                  // row within 16-row slab
  const int swzs = (((l & 3) - (l >> 3)) & 3) * 16;        // pre-swizzled source byte offset

  const char* pA;
  const char* pB[NG];
  auto initA = [&](const u16* A, long lda) {
    pA = (const char*)A + ((bm + w * 16 + l4q) * lda) * 2 + swzs;
  };
  auto initB = [&](const u16* W, int wld) {
#pragma unroll
    for (int c = 0; c < NG; ++c) {
      const int brow = (w * NG + c) * 16 + l4q;
      const long wrow = (long)(brow >> 6) * gs + (long)yb * ys + (brow & 63);
      pB[c] = (const char*)W + (wrow * (long)wld) * 2 + swzs;
    }
  };
  auto stage = [&](int buf) {
    gload16(pA, &As[buf][(w * 16) * 32]);
    pA += 64;
#pragma unroll
    for (int c = 0; c < NG; ++c) {
      gload16(pB[c], &Bs[buf][((w * NG + c) * 16) * 32]);
      pB[c] += 64;
    }
  };

  initA(A1, lda1);
  initB(W1, wld1);
  stage(0);

  const int rb = l & 15;
  const int koff = ((((l >> 4) + ((l & 15) >> 1)) & 3) * 8);   // slot-swizzled read offset
  int cur = 0;
  for (int ch = 0; ch < nt; ++ch) {
    __syncthreads();                       // buf[cur] staged; prior reads drained
    if (ch + 1 < nt) {
      if (A2 && ch + 1 == nch1) { initA(A2, lda2); initB(W2, wld2); }
      stage(cur ^ 1);
    }
    const u16* Ab = As[cur];
    const u16* Bb = Bs[cur];
    bf16x8 af[4];
#pragma unroll
    for (int rf = 0; rf < 4; ++rf)
      af[rf] = *(const bf16x8*)&Ab[(rf * 16 + rb) * 32 + koff];
#pragma unroll
    for (int g = 0; g < NG; ++g) {
      bf16x8 bfr = *(const bf16x8*)&Bb[(g * 64 + w * 16 + rb) * 32 + koff];
#pragma unroll
      for (int rf = 0; rf < 4; ++rf)
        acc[rf][g] = __builtin_amdgcn_mfma_f32_16x16x32_bf16(af[rf], bfr, acc[rf][g], 0, 0, 0);
    }
    cur ^= 1;
  }

  if constexpr (EPI == 0) {
#pragma unroll
    for (int g = 0; g < NG; ++g) {
      const int wrow = g * gs + yb * ys + w * 16 + colb;
#pragma unroll
      for (int rf = 0; rf < 4; ++rf) {
#pragma unroll
        for (int r = 0; r < 4; ++r) {
          float vv = acc[rf][g][r];
          if (relu) vv = fmaxf(vv, 0.f);
          out0[(bm + rf * 16 + rq * 4 + r) * (long)ldo + wrow] = f2b(vv);
        }
      }
    }
  } else {
    const int cb = yb * ys + w * 16 + colb;
#pragma unroll
    for (int rf = 0; rf < 4; ++rf) {
#pragma unroll
      for (int r = 0; r < 4; ++r) {
        const long row = bm + rf * 16 + rq * 4 + r;
        const float zi = acc[rf][0][r];
        const float zf = acc[rf][1][r];
        const float zg = acc[rf][2][r];
        const float zo = acc[rf][3][r];
        const float cp = cprev ? cprev[row * 256 + cb] : 0.f;
        const float cn = sigf(zf) * cp + sigf(zi) * tanh_f(zg);
        const float hn = sigf(zo) * tanh_f(cn);
        cout[row * 256 + cb] = cn;
        hout[row * (long)ldh + cb] = f2b(hn);
      }
    }
  }
}

// ---------------- fused q-GEMM + attention ----------------
// Block: 64 rows x 256 cols (full q rows). GEMM identical to mfma_gemm7
// (NG=4, gs=64, yb=0). q goes to LDS (bf16, stride 260) instead of global;
// attention epilogue: each wave serially handles 16 rows; per row 64 lanes x
// 4 cols compute scores over T=3, softmax, context -> dec_in[:, 6:262].
__global__ __launch_bounds__(256, 2)
void qattn_kernel(const u16* __restrict__ A1, long lda1,
                  const u16* __restrict__ W1, int wld1,
                  const float* __restrict__ bias,
                  const u16* __restrict__ ep, const u16* __restrict__ eo,
                  const float* __restrict__ va, const float* __restrict__ ba,
                  u16* __restrict__ dec_in)
{
  __shared__ u16 As[2][64 * 32];
  __shared__ u16 Bs[2][4 * 64 * 32];
  __shared__ u16 qs[64 * 260];             // q tile bf16, row stride 260
  const int tid = threadIdx.x;
  const int l = tid & 63, w = tid >> 6;
  const long bm = (long)blockIdx.x * 64;
  const int nt = 8;                        // K = 256

  const int colb = l & 15, rq = l >> 4;

  f32x4 acc[4][4];
  {
    float bw[4];
#pragma unroll
    for (int g = 0; g < 4; ++g) bw[g] = bias[g * 64 + w * 16 + colb];
#pragma unroll
    for (int rf = 0; rf < 4; ++rf)
#pragma unroll
      for (int g = 0; g < 4; ++g) acc[rf][g] = (f32x4){bw[g], bw[g], bw[g], bw[g]};
  }

  const int l4q = l >> 2;
  const int swzs = (((l & 3) - (l >> 3)) & 3) * 16;

  const char* pA = (const char*)A1 + ((bm + w * 16 + l4q) * lda1) * 2 + swzs;
  const char* pB[4];
#pragma unroll
  for (int c = 0; c < 4; ++c) {
    const int brow = (w * 4 + c) * 16 + l4q;
    pB[c] = (const char*)W1 + ((long)brow * wld1) * 2 + swzs;
  }
  auto stage = [&](int buf) {
    gload16(pA, &As[buf][(w * 16) * 32]);
    pA += 64;
#pragma unroll
    for (int c = 0; c < 4; ++c) {
      gload16(pB[c], &Bs[buf][((w * 4 + c) * 16) * 32]);
      pB[c] += 64;
    }
  };

  stage(0);
  const int rb = l & 15;
  const int koff = ((((l >> 4) + ((l & 15) >> 1)) & 3) * 8);
  int cur = 0;
  for (int ch = 0; ch < nt; ++ch) {
    __syncthreads();
    if (ch + 1 < nt) stage(cur ^ 1);
    const u16* Ab = As[cur];
    const u16* Bb = Bs[cur];
    bf16x8 af[4];
#pragma unroll
    for (int rf = 0; rf < 4; ++rf)
      af[rf] = *(const bf16x8*)&Ab[(rf * 16 + rb) * 32 + koff];
#pragma unroll
    for (int g = 0; g < 4; ++g) {
      bf16x8 bfr = *(const bf16x8*)&Bb[(g * 64 + w * 16 + rb) * 32 + koff];
#pragma unroll
      for (int rf = 0; rf < 4; ++rf)
        acc[rf][g] = __builtin_amdgcn_mfma_f32_16x16x32_bf16(af[rf], bfr, acc[rf][g], 0, 0, 0);
    }
    cur ^= 1;
  }

  // q -> LDS
#pragma unroll
  for (int g = 0; g < 4; ++g) {
    const int col = g * 64 + w * 16 + colb;
#pragma unroll
    for (int rf = 0; rf < 4; ++rf)
#pragma unroll
      for (int r = 0; r < 4; ++r)
        qs[(rf * 16 + rq * 4 + r) * 260 + col] = f2b(acc[rf][g][r]);
  }
  __syncthreads();

  // attention: wave w handles rows w*16 .. w*16+15
  const float ba0 = ba[0];
  const int c = l * 4;
  float vav[4];
  {
    float4 vv = *(const float4*)&va[c];
    vav[0] = vv.x; vav[1] = vv.y; vav[2] = vv.z; vav[3] = vv.w;
  }
  for (int rr = 0; rr < 16; ++rr) {
    const int lrow = w * 16 + rr;
    const long row = bm + lrow;
    float qv[4];
    {
      ushort4 qu = *(const ushort4*)&qs[lrow * 260 + c];
      qv[0] = b2f(qu.x); qv[1] = b2f(qu.y); qv[2] = b2f(qu.z); qv[3] = b2f(qu.w);
    }
    float s[3];
#pragma unroll
    for (int t = 0; t < 3; ++t) {
      ushort4 eu = *(const ushort4*)&ep[row * 768 + t * 256 + c];
      float p = tanh_f(qv[0] + b2f(eu.x)) * vav[0]
              + tanh_f(qv[1] + b2f(eu.y)) * vav[1]
              + tanh_f(qv[2] + b2f(eu.z)) * vav[2]
              + tanh_f(qv[3] + b2f(eu.w)) * vav[3];
#pragma unroll
      for (int m = 32; m; m >>= 1) p += __shfl_xor(p, m);
      s[t] = p + ba0;
    }
    const float mx = fmaxf(s[0], fmaxf(s[1], s[2]));
    const float e0 = __expf(s[0] - mx), e1 = __expf(s[1] - mx), e2 = __expf(s[2] - mx);
    const float inv = rcpf(e0 + e1 + e2);
    const float w0 = e0 * inv, w1 = e1 * inv, w2 = e2 * inv;
    const ushort4 a0 = *(const ushort4*)&eo[row * 768 + 0 * 256 + c];
    const ushort4 a1 = *(const ushort4*)&eo[row * 768 + 1 * 256 + c];
    const ushort4 a2 = *(const ushort4*)&eo[row * 768 + 2 * 256 + c];
    u16* dp = &dec_in[row * 416 + 6 + c];
    dp[0] = f2b(w0 * b2f(a0.x) + w1 * b2f(a1.x) + w2 * b2f(a2.x));
    dp[1] = f2b(w0 * b2f(a0.y) + w1 * b2f(a1.y) + w2 * b2f(a2.y));
    dp[2] = f2b(w0 * b2f(a0.z) + w1 * b2f(a1.z) + w2 * b2f(a2.z));
    dp[3] = f2b(w0 * b2f(a0.w) + w1 * b2f(a1.w) + w2 * b2f(a2.w));
  }
}

// ---------------- fused t1-GEMM + delta ----------------
// Block: 64 rows x 128 cols (full t1 rows). GEMM (NG=2) -> relu -> t1 to LDS
// (stride 136); then delta = t1 @ Wo2^T + bo2, pred = last + delta -> out +
// dec_in[:, 0:6].
__global__ __launch_bounds__(256, 2)
void t1delta_kernel(const u16* __restrict__ A1, long lda1,
                    const u16* __restrict__ W1, int wld1,
                    const float* __restrict__ bias,
                    const float* __restrict__ Wo2, const float* __restrict__ bo2,
                    const float* __restrict__ lastp, int lstride,
                    float* __restrict__ outp, int ostride,
                    u16* __restrict__ dec_in)
{
  __shared__ u16 As[2][64 * 32];
  __shared__ u16 Bs[2][2 * 64 * 32];
  __shared__ u16 t1s[64 * 136];            // t1 tile bf16, row stride 136
  __shared__ float w2s[768];
  __shared__ float part[64][4][6];
  const int tid = threadIdx.x;
  const int l = tid & 63, w = tid >> 6;
  const long bm = (long)blockIdx.x * 64;
  const int nt = 8;                        // K = 256

  for (int i = tid; i < 768; i += 256) w2s[i] = Wo2[i];

  const int colb = l & 15, rq = l >> 4;

  f32x4 acc[4][2];
  {
    float bw[2];
#pragma unroll
    for (int g = 0; g < 2; ++g) bw[g] = bias[g * 64 + w * 16 + colb];
#pragma unroll
    for (int rf = 0; rf < 4; ++rf)
#pragma unroll
      for (int g = 0; g < 2; ++g) acc[rf][g] = (f32x4){bw[g], bw[g], bw[g], bw[g]};
  }

  const int l4q = l >> 2;
  const int swzs = (((l & 3) - (l >> 3)) & 3) * 16;

  const char* pA = (const char*)A1 + ((bm + w * 16 + l4q) * lda1) * 2 + swzs;
  const char* pB[2];
#pragma unroll
  for (int c = 0; c < 2; ++c) {
    const int brow = (w * 2 + c) * 16 + l4q;
    pB[c] = (const char*)W1 + ((long)brow * wld1) * 2 + swzs;
  }
  auto stage = [&](int buf) {
    gload16(pA, &As[buf][(w * 16) * 32]);
    pA += 64;
#pragma unroll
    for (int c = 0; c < 2; ++c) {
      gload16(pB[c], &Bs[buf][((w * 2 + c) * 16) * 32]);
      pB[c] += 64;
    }
  };

  stage(0);
  const int rb = l & 15;
  const int koff = ((((l >> 4) + ((l & 15) >> 1)) & 3) * 8);
  int cur = 0;
  for (int ch = 0; ch < nt; ++ch) {
    __syncthreads();
    if (ch + 1 < nt) stage(cur ^ 1);
    const u16* Ab = As[cur];
    const u16* Bb = Bs[cur];
    bf16x8 af[4];
#pragma unroll
    for (int rf = 0; rf < 4; ++rf)
      af[rf] = *(const bf16x8*)&Ab[(rf * 16 + rb) * 32 + koff];
#pragma unroll
    for (int g = 0; g < 2; ++g) {
      bf16x8 bfr = *(const bf16x8*)&Bb[(g * 64 + w * 16 + rb) * 32 + koff];
#pragma unroll
      for (int rf = 0; rf < 4; ++rf)
        acc[rf][g] = __builtin_amdgcn_mfma_f32_16x16x32_bf16(af[rf], bfr, acc[rf][g], 0, 0, 0);
    }
    cur ^= 1;
  }

  // relu(t1) -> LDS
#pragma unroll
  for (int g = 0; g < 2; ++g) {
    const int col = g * 64 + w * 16 + colb;
#pragma unroll
    for (int rf = 0; rf < 4; ++rf)
#pragma unroll
      for (int r = 0; r < 4; ++r)
        t1s[(rf * 16 + rq * 4 + r) * 136 + col] = f2b(fmaxf(acc[rf][g][r], 0.f));
  }
  __syncthreads();

  // delta phase
  const int rw = tid >> 2, q = tid & 3;
  float p[6] = {0.f, 0.f, 0.f, 0.f, 0.f, 0.f};
  const u16* tp = &t1s[rw * 136 + q * 32];
#pragma unroll
  for (int it = 0; it < 4; ++it) {
    int4 chunk = *(const int4*)&tp[it * 8];
    const u16* cu = (const u16*)&chunk;
#pragma unroll
    for (int e = 0; e < 8; ++e) {
      const float tv = b2f(cu[e]);
      const int k = q * 32 + it * 8 + e;
#pragma unroll
      for (int j = 0; j < 6; ++j) p[j] += tv * w2s[j * 128 + k];
    }
  }
#pragma unroll
  for (int j = 0; j < 6; ++j) part[rw][q][j] = p[j];
  __syncthreads();
  if (tid < 64) {
    const long r2 = bm + tid;
#pragma unroll
    for (int j = 0; j < 6; ++j) {
      const float d = bo2[j] + part[tid][0][j] + part[tid][1][j] + part[tid][2][j] + part[tid][3][j];
      const float pr = lastp[r2 * lstride + j] + d;
      outp[r2 * ostride + j] = pr;
      dec_in[r2 * 416 + j] = f2b(pr);
    }
  }
}

// ---------------- fused front: baseline MLP+LN, last_cbc, zpad, xbf cvt ----------------
__global__ __launch_bounds__(256)
void front_kernel(const float* __restrict__ cbc, const float* __restrict__ baseline,
                  const float* __restrict__ Wb, const float* __restrict__ bb,
                  const float* __restrict__ ln_g, const float* __restrict__ ln_b,
                  u16* __restrict__ dec_in, u16* __restrict__ xbf)
{
  __shared__ float wbs[1280];
  __shared__ float bbs[128], lgs[128], lbs[128];
  const int tid = threadIdx.x;
  for (int i = tid; i < 1280; i += 256) wbs[i] = Wb[i];
  if (tid < 128) { bbs[tid] = bb[tid]; lgs[tid] = ln_g[tid]; lbs[tid] = ln_b[tid]; }
  __syncthreads();
  const int l = tid & 63, w = tid >> 6;
  const long row = (long)blockIdx.x * 4 + w;
#pragma unroll
  for (int e = l; e < 96; e += 64) {
    const int t = e >> 5, c = e & 31;
    xbf[(row * 3 + t) * 32 + c] = (c < 6) ? f2b(cbc[row * 18 + t * 6 + c]) : (u16)0;
  }
  if (l < 6) dec_in[row * 416 + l] = f2b(cbc[row * 18 + 12 + l]);
  else if (l < 32) dec_in[row * 416 + 390 + (l - 6)] = 0;
  float bl[10];
#pragma unroll
  for (int k = 0; k < 10; ++k) bl[k] = baseline[row * 10 + k];
  const int c0 = l, c1 = l + 64;
  float z0 = bbs[c0], z1 = bbs[c1];
#pragma unroll
  for (int k = 0; k < 10; ++k) { z0 += bl[k] * wbs[c0 * 10 + k]; z1 += bl[k] * wbs[c1 * 10 + k]; }
  z0 = fmaxf(z0, 0.f); z1 = fmaxf(z1, 0.f);
  float s = z0 + z1, sq = z0 * z0 + z1 * z1;
#pragma unroll
  for (int m = 32; m; m >>= 1) { s += __shfl_xor(s, m); sq += __shfl_xor(sq, m); }
  const float mu = s * (1.f / 128.f);
  const float var = sq * (1.f / 128.f) - mu * mu;
  const float rs = rsqrtf(var + 1e-5f);
  dec_in[row * 416 + 262 + c0] = f2b((z0 - mu) * rs * lgs[c0] + lbs[c0]);
  dec_in[row * 416 + 262 + c1] = f2b((z1 - mu) * rs * lgs[c1] + lbs[c1]);
}

extern "C" void kernel_launch(void* const* d_in, const int* in_sizes, int n_in,
                              void* d_out, int out_size, void* d_ws, size_t ws_size,
                              hipStream_t stream) {
  const float* cbc   = (const float*)d_in[0];
  const float* base  = (const float*)d_in[1];
  const float* W_ih0 = (const float*)d_in[2];
  const float* W_hh0 = (const float*)d_in[3];
  const float* b_ih0 = (const float*)d_in[4];
  const float* b_hh0 = (const float*)d_in[5];
  const float* W_ih1 = (const float*)d_in[6];
  const float* W_hh1 = (const float*)d_in[7];
  const float* b_ih1 = (const float*)d_in[8];
  const float* b_hh1 = (const float*)d_in[9];
  const float* Wb    = (const float*)d_in[10];
  const float* bb    = (const float*)d_in[11];
  const float* ln_g  = (const float*)d_in[12];
  const float* ln_b  = (const float*)d_in[13];
  const float* W1a   = (const float*)d_in[14];
  const float* b1a   = (const float*)d_in[15];
  const float* W2a   = (const float*)d_in[16];
  const float* b2a   = (const float*)d_in[17];
  const float* va    = (const float*)d_in[18];
  const float* ba    = (const float*)d_in[19];
  const float* Wd_ih = (const float*)d_in[20];
  const float* Wd_hh = (const float*)d_in[21];
  const float* bd_ih = (const float*)d_in[22];
  const float* bd_hh = (const float*)d_in[23];
  const float* Wo1   = (const float*)d_in[24];
  const float* bo1   = (const float*)d_in[25];
  const float* Wo2   = (const float*)d_in[26];
  const float* bo2   = (const float*)d_in[27];
  float* out = (float*)d_out;
  (void)in_sizes; (void)n_in; (void)out_size;

  unsigned char* wsb = (unsigned char*)d_ws;
  size_t off = 0;
  auto alloc = [&](size_t bytes) -> void* {
    void* p = wsb + off;
    off += (bytes + 255) & ~(size_t)255;
    return p;
  };
  // ---- persistent (weights, biases) ----
  u16* wih0b = (u16*)alloc(1024 * 32 * 2);    // padded K 6->32
  u16* whh0b = (u16*)alloc(1024 * 256 * 2);
  u16* wih1b = (u16*)alloc(1024 * 256 * 2);
  u16* whh1b = (u16*)alloc(1024 * 256 * 2);
  u16* wdihb = (u16*)alloc(1024 * 416 * 2);   // padded K 390->416
  u16* wdhhb = (u16*)alloc(1024 * 256 * 2);
  u16* w1ab  = (u16*)alloc(256 * 256 * 2);
  u16* w2ab  = (u16*)alloc(256 * 256 * 2);
  u16* wo1b  = (u16*)alloc(128 * 256 * 2);
  float* bsum0 = (float*)alloc(1024 * 4);
  float* bsum1 = (float*)alloc(1024 * 4);
  float* bsumd = (float*)alloc(1024 * 4);

  // ---- batch chunking: per-row bytes; R multiple of 512 (XCD remap needs nb%8==0) ----
  const long perRow = 6656;
  long avail = (long)ws_size - (long)off - 32768;
  long R = avail > 0 ? avail / perRow : 512;
  R &= ~511L;
  if (R > BATCH) R = BATCH;
  if (R < 512) R = 512;

  u16* xbf    = (u16*)alloc((size_t)R * 96 * 2);    // [R*3][32] padded
  u16* y0     = (u16*)alloc((size_t)R * 768 * 2);   // layer0 outputs; later enc_proj
  u16* y1     = (u16*)alloc((size_t)R * 768 * 2);   // layer1 outputs = encoder_outputs
  float* cbuf = (float*)alloc((size_t)R * 256 * 4); // c row-major [row][256]
  u16* hdec0  = (u16*)alloc((size_t)R * 256 * 2);
  u16* hdec1  = (u16*)alloc((size_t)R * 256 * 2);
  u16* qt1    = (u16*)alloc((size_t)R * 256 * 2);   // (kept for layout stability; unused)
  u16* dec_in = (u16*)alloc((size_t)R * 416 * 2);   // [R][416], cols 390..415 zero
  (void)qt1;

  // ---- fused prep (single launch) ----
  {
    PrepP p;
    const float* ss[9] = {W_ih0, W_hh0, W_ih1, W_hh1, Wd_ih, Wd_hh, W1a, W2a, Wo1};
    u16* dd[9]         = {wih0b, whh0b, wih1b, whh1b, wdihb, wdhhb, w1ab, w2ab, wo1b};
    int scv[9]         = {6, 256, 256, 256, 390, 256, 256, 256, 256};
    int dcv[9]         = {32, 256, 256, 256, 416, 256, 256, 256, 256};
    long rows[9]       = {1024, 1024, 1024, 1024, 1024, 1024, 256, 256, 128};
    long cvtTotal = 0;
    for (int i = 0; i < 9; ++i) {
      p.s[i] = ss[i]; p.d[i] = dd[i]; p.sc[i] = scv[i]; p.dc[i] = dcv[i];
      p.n[i] = rows[i] * dcv[i]; cvtTotal += p.n[i];
    }
    p.ba[0] = b_ih0; p.bb_[0] = b_hh0; p.bo[0] = bsum0;
    p.ba[1] = b_ih1; p.bb_[1] = b_hh1; p.bo[1] = bsum1;
    p.ba[2] = bd_ih; p.bb_[2] = bd_hh; p.bo[2] = bsumd;
    prep_kernel<<<dim3(2048), dim3(256), 0, stream>>>(p, cvtTotal, cvtTotal + 3072);
  }

  const dim3 blk(256);

  for (long r0 = 0; r0 < BATCH; r0 += R) {
    const long Rc = (BATCH - r0 < R) ? (BATCH - r0) : R;
    const unsigned nb = (unsigned)(Rc / 64);
    const dim3 gcell(nb * 4);                 // 1D, XCD-remapped in-kernel
    const float* cbc_c  = cbc + r0 * 18;
    const float* base_c = base + r0 * 10;
    float* out_c = out + r0 * 30;

    front_kernel<<<dim3((unsigned)(Rc / 4)), blk, 0, stream>>>(
        cbc_c, base_c, Wb, bb, ln_g, ln_b, dec_in, xbf);

    // ---- encoder layer 0 (K1 padded to 32) ----
    for (int t = 0; t < 3; ++t) {
      const u16* a2 = t ? (y0 + (t - 1) * 256) : nullptr;
      mfma_gemm7<1, 4, 1, 4><<<gcell, blk, 0, stream>>>(
          xbf + t * 32, 96, 32, wih0b, 32,
          a2, 768, 256, whh0b, 256,
          256, 64, bsum0,
          nullptr, 0, 0,
          (t ? cbuf : nullptr), cbuf, y0 + t * 256, 768);
    }
    // ---- encoder layer 1 ----
    for (int t = 0; t < 3; ++t) {
      const u16* a2 = t ? (y1 + (t - 1) * 256) : nullptr;
      mfma_gemm7<1, 4, 1, 4><<<gcell, blk, 0, stream>>>(
          y0 + t * 256, 768, 256, wih1b, 256,
          a2, 768, 256, whh1b, 256,
          256, 64, bsum1,
          nullptr, 0, 0,
          (t ? cbuf : nullptr), cbuf, y1 + t * 256, 768);
    }
    // ---- enc_proj = encoder_outputs @ W2a^T + b2a (into y0, now dead) ----
    mfma_gemm7<0, 4, 0, 3><<<dim3(nb * 3, 1), blk, 0, stream>>>(
        y1, 256, 256, w2ab, 256,
        nullptr, 0, 0, nullptr, 0,
        64, 0, b2a,
        y0, 256, 0,
        nullptr, nullptr, nullptr, 0);

    // ---- decoder ----
    const u16* hcur = y1 + 2 * 256; long hld = 768;   // hT
    for (int s = 0; s < 5; ++s) {
      // fused q-GEMM + attention -> dec_in[:, 6:262]
      qattn_kernel<<<dim3(nb), blk, 0, stream>>>(
          hcur, hld, w1ab, 256, b1a, y0, y1, va, ba, dec_in);
      // decoder LSTM cell (K1 padded to 416)
      u16* hnext = (s & 1) ? hdec1 : hdec0;
      mfma_gemm7<1, 4, 1, 4><<<gcell, blk, 0, stream>>>(
          dec_in, 416, 416, wdihb, 416,
          hcur, hld, 256, wdhhb, 256,
          256, 64, bsumd,
          nullptr, 0, 0,
          cbuf, cbuf, hnext, 256);
      hcur = hnext; hld = 256;
      // fused t1-GEMM + delta + pred
      const float* lastp = (s == 0) ? (cbc_c + 12) : (out_c + (long)(s - 1) * 6);
      const int lstr = (s == 0) ? 18 : 30;
      t1delta_kernel<<<dim3(nb), blk, 0, stream>>>(
          hcur, 256, wo1b, 256, bo1,
          Wo2, bo2, lastp, lstr, out_c + (long)s * 6, 30, dec_in);
    }
  }
}

// Round 13
// 842.435 us; speedup vs baseline: 1.2864x; 1.0465x over previous
//
#include <hip/hip_runtime.h>

typedef unsigned short u16;
typedef __bf16 bf16x8 __attribute__((ext_vector_type(8)));
typedef float f32x4 __attribute__((ext_vector_type(4)));

#define BATCH 32768L

__device__ __forceinline__ u16 f2b(float f) {
  union { float f; unsigned int u; } v; v.f = f;
  unsigned int r = v.u + 0x7fffu + ((v.u >> 16) & 1u);
  return (u16)(r >> 16);
}
__device__ __forceinline__ float b2f(u16 h) {
  union { unsigned int u; float f; } v; v.u = ((unsigned int)h) << 16;
  return v.f;
}
__device__ __forceinline__ float rcpf(float x) { return __builtin_amdgcn_rcpf(x); }
__device__ __forceinline__ float sigf(float x) {
  return rcpf(1.f + __builtin_amdgcn_exp2f(-1.442695041f * x));
}
__device__ __forceinline__ float tanh_f(float x) {
  return 1.f - 2.f * rcpf(1.f + __builtin_amdgcn_exp2f(2.885390082f * x));
}

__device__ __forceinline__ void gload16(const void* g, void* l) {
  __builtin_amdgcn_global_load_lds((const __attribute__((address_space(1))) unsigned int*)g,
                                   (__attribute__((address_space(3))) unsigned int*)l,
                                   16, 0, 0);
}

// ---------------- fused prep ----------------
struct PrepP {
  const float* s[9]; u16* d[9]; int sc[9]; int dc[9]; long n[9];
  const float* ba[3]; const float* bb_[3]; float* bo[3];
};

__global__ void prep_kernel(PrepP p, long cvtTotal, long total) {
  for (long i = (long)blockIdx.x * blockDim.x + threadIdx.x; i < total;
       i += (long)gridDim.x * blockDim.x) {
    if (i < cvtTotal) {
      long off = i; int sg = 0;
      while (off >= p.n[sg]) { off -= p.n[sg]; ++sg; }
      long r = off / p.dc[sg]; int c = (int)(off - r * p.dc[sg]);
      p.d[sg][off] = (c < p.sc[sg]) ? f2b(p.s[sg][r * (long)p.sc[sg] + c]) : (u16)0;
    } else {
      long j = i - cvtTotal; int sg = (int)(j >> 10); int k = (int)(j & 1023);
      p.bo[sg][k] = p.ba[sg][k] + p.bb_[sg][k];
    }
  }
}

// ---------------- LSTM cell GEMM, 3-slot depth-2 counted-vmcnt pipeline ----------------
// Block: 128 rows x 256 cols, 4 waves, BK=32, K = K1 + K2 (each mult of 32).
// Column mapping (gate-interleaved): block col = hb*64 + g*16 + i  ->
// W row = g*256 + yb*64 + hb*16 + i. Wave w owns hidden block w (16 hidden
// cols, all 4 gates) x all 128 rows: acc[8 rowfrag][4 gate].
// LDS: 3 slots x (A 128x32 + B 256x32) = 72KB -> 2 blocks/CU.
// Pipeline: tiles prefetched 2 ahead (6 gloads/tile: 2 A + 4 B), tile start
// waits `s_waitcnt vmcnt(6)` (only last tile drains to 0) + s_barrier.
// Slot swizzle (verified 0 conflicts in r9): unit u of row r at slot
// (u+(r>>1))&3; linear HW writes -> per-lane global source unit
// ((tid&3)-(tid>>3))&3; reads slot ((l>>4)+((l&15)>>1))&3.
// XCD remap: grid 1D (R/128)*4, rb=(vid>>5)*8+(vid&7), yb=(vid>>3)&3.
__global__ __launch_bounds__(256, 2)
void cell_gemm(const u16* __restrict__ A1, long lda1, int K1,
               const u16* __restrict__ W1, int wld1,
               const u16* __restrict__ A2, long lda2, int K2,
               const u16* __restrict__ W2, int wld2,
               const float* __restrict__ bias,
               const float* __restrict__ cprev, float* __restrict__ cout,
               u16* __restrict__ hout, int ldh)
{
  __shared__ u16 As[3][128 * 32];
  __shared__ u16 Bs[3][256 * 32];
  const int tid = threadIdx.x;
  const int l = tid & 63, w = tid >> 6;
  const int vid = blockIdx.x;
  const int rbk = (vid >> 5) * 8 + (vid & 7);
  const int yb = (vid >> 3) & 3;
  const long bm = (long)rbk * 128;

  const int nch1 = K1 >> 5;
  const int nch2 = A2 ? (K2 >> 5) : 0;
  const int nt = nch1 + nch2;

  const int colb = l & 15, rq = l >> 4;
  const int cb = yb * 64 + w * 16 + colb;

  f32x4 acc[8][4];
  {
    float bw[4];
#pragma unroll
    for (int g = 0; g < 4; ++g) bw[g] = bias[g * 256 + cb];
#pragma unroll
    for (int rf = 0; rf < 8; ++rf)
#pragma unroll
      for (int g = 0; g < 4; ++g) acc[rf][g] = (f32x4){bw[g], bw[g], bw[g], bw[g]};
  }

  const int srow = tid >> 2;                           // row within 64-row gload slab
  const int srcu = (((tid & 3) - (tid >> 3)) & 3) * 16;  // pre-swizzled source byte offset

  const char* pA0; const char* pA1_;
  const char* pB[4];
  auto initAp = [&](const u16* A, long lda) {
    pA0  = (const char*)A + ((bm + srow) * lda) * 2 + srcu;
    pA1_ = (const char*)A + ((bm + 64 + srow) * lda) * 2 + srcu;
  };
  auto initBp = [&](const u16* W, int wld) {
#pragma unroll
    for (int j = 0; j < 4; ++j) {
      const long wrow = (long)(tid >> 6) * 256 + yb * 64 + j * 16 + ((tid >> 2) & 15);
      pB[j] = (const char*)W + (wrow * (long)wld) * 2 + srcu;
    }
  };
  auto issueA = [&](int s, int sl) {
    if (s == nch1) initAp(A2, lda2);
    gload16(pA0, &As[sl][w * 512]); pA0 += 64;
    gload16(pA1_, &As[sl][2048 + w * 512]); pA1_ += 64;
  };
  auto issueB = [&](int s, int sl) {
    if (s == nch1) initBp(W2, wld2);
#pragma unroll
    for (int j = 0; j < 4; ++j) {
      gload16(pB[j], &Bs[sl][j * 2048 + w * 512]); pB[j] += 64;
    }
  };

  initAp(A1, lda1);
  initBp(W1, wld1);
  issueA(0, 0); issueB(0, 0);
  if (nt > 1) { issueA(1, 1); issueB(1, 1); }

  const int rb = l & 15;
  const int koff = (((l >> 4) + ((l & 15) >> 1)) & 3) * 8;
  int slot = 0;
  for (int ch = 0; ch < nt; ++ch) {
    if (ch + 1 < nt) {
      asm volatile("s_waitcnt vmcnt(6)\n\ts_barrier" ::: "memory");
    } else {
      asm volatile("s_waitcnt vmcnt(0)\n\ts_barrier" ::: "memory");
    }
    const int nsl = (slot + 2 >= 3) ? slot - 1 : slot + 2;
    const u16* Ab = As[slot];
    const u16* Bb = Bs[slot];
    bf16x8 af[8];
#pragma unroll
    for (int rf = 0; rf < 8; ++rf)
      af[rf] = *(const bf16x8*)&Ab[(rf * 16 + rb) * 32 + koff];
    bf16x8 bf0 = *(const bf16x8*)&Bb[(w * 64 + rb) * 32 + koff];
    bf16x8 bf1 = *(const bf16x8*)&Bb[(w * 64 + 16 + rb) * 32 + koff];
    if (ch + 2 < nt) issueA(ch + 2, nsl);
    __builtin_amdgcn_s_setprio(1);
#pragma unroll
    for (int rf = 0; rf < 8; ++rf)
      acc[rf][0] = __builtin_amdgcn_mfma_f32_16x16x32_bf16(af[rf], bf0, acc[rf][0], 0, 0, 0);
#pragma unroll
    for (int rf = 0; rf < 8; ++rf)
      acc[rf][1] = __builtin_amdgcn_mfma_f32_16x16x32_bf16(af[rf], bf1, acc[rf][1], 0, 0, 0);
    __builtin_amdgcn_s_setprio(0);
    bf16x8 bf2 = *(const bf16x8*)&Bb[(w * 64 + 32 + rb) * 32 + koff];
    bf16x8 bf3 = *(const bf16x8*)&Bb[(w * 64 + 48 + rb) * 32 + koff];
    if (ch + 2 < nt) issueB(ch + 2, nsl);
    __builtin_amdgcn_s_setprio(1);
#pragma unroll
    for (int rf = 0; rf < 8; ++rf)
      acc[rf][2] = __builtin_amdgcn_mfma_f32_16x16x32_bf16(af[rf], bf2, acc[rf][2], 0, 0, 0);
#pragma unroll
    for (int rf = 0; rf < 8; ++rf)
      acc[rf][3] = __builtin_amdgcn_mfma_f32_16x16x32_bf16(af[rf], bf3, acc[rf][3], 0, 0, 0);
    __builtin_amdgcn_s_setprio(0);
    slot = (slot + 1 == 3) ? 0 : slot + 1;
  }

  // LSTM gating epilogue (per-wave, all 4 gates local)
#pragma unroll
  for (int rf = 0; rf < 8; ++rf) {
#pragma unroll
    for (int r = 0; r < 4; ++r) {
      const long row = bm + rf * 16 + rq * 4 + r;
      const float zi = acc[rf][0][r];
      const float zf = acc[rf][1][r];
      const float zg = acc[rf][2][r];
      const float zo = acc[rf][3][r];
      const float cp = cprev ? cprev[row * 256 + cb] : 0.f;
      const float cn = sigf(zf) * cp + sigf(zi) * tanh_f(zg);
      const float hn = sigf(zo) * tanh_f(cn);
      cout[row * 256 + cb] = cn;
      hout[row * (long)ldh + cb] = f2b(hn);
    }
  }
}

// ---------------- old-style MFMA GEMM (kept for enc_proj) ----------------
template <int EPI, int NG, int REMAP, int MINW>
__global__ __launch_bounds__(256, MINW)
void mfma_gemm7(const u16* __restrict__ A1, long lda1, int K1,
                const u16* __restrict__ W1, int wld1,
                const u16* __restrict__ A2, long lda2, int K2,
                const u16* __restrict__ W2, int wld2,
                int gs, int ys, const float* __restrict__ bias,
                u16* __restrict__ out0, int ldo, int relu,
                const float* __restrict__ cprev, float* __restrict__ cout,
                u16* __restrict__ hout, int ldh)
{
  __shared__ u16 As[2][64 * 32];
  __shared__ u16 Bs[2][NG * 64 * 32];
  const int tid = threadIdx.x;
  const int l = tid & 63, w = tid >> 6;

  int row_blk, yb;
  if constexpr (REMAP) {
    const int vid = blockIdx.x;
    row_blk = (vid >> 5) * 8 + (vid & 7);
    yb = (vid >> 3) & 3;
  } else {
    row_blk = blockIdx.x;
    yb = blockIdx.y;
  }
  const long bm = (long)row_blk * 64;

  const int nch1 = K1 >> 5;
  const int nch2 = A2 ? (K2 >> 5) : 0;
  const int nt = nch1 + nch2;

  const int colb = l & 15, rq = l >> 4;

  f32x4 acc[4][NG];
  {
    float bw[NG];
#pragma unroll
    for (int g = 0; g < NG; ++g) bw[g] = bias[g * gs + yb * ys + w * 16 + colb];
#pragma unroll
    for (int rf = 0; rf < 4; ++rf)
#pragma unroll
      for (int g = 0; g < NG; ++g) acc[rf][g] = (f32x4){bw[g], bw[g], bw[g], bw[g]};
  }

  const int l4q = l >> 2;
  const int swzs = (((l & 3) - (l >> 3)) & 3) * 16;

  const char* pA;
  const char* pB[NG];
  auto initA = [&](const u16* A, long lda) {
    pA = (const char*)A + ((bm + w * 16 + l4q) * lda) * 2 + swzs;
  };
  auto initB = [&](const u16* W, int wld) {
#pragma unroll
    for (int c = 0; c < NG; ++c) {
      const int brow = (w * NG + c) * 16 + l4q;
      const long wrow = (long)(brow >> 6) * gs + (long)yb * ys + (brow & 63);
      pB[c] = (const char*)W + (wrow * (long)wld) * 2 + swzs;
    }
  };
  auto stage = [&](int buf) {
    gload16(pA, &As[buf][(w * 16) * 32]);
    pA += 64;
#pragma unroll
    for (int c = 0; c < NG; ++c) {
      gload16(pB[c], &Bs[buf][((w * NG + c) * 16) * 32]);
      pB[c] += 64;
    }
  };

  initA(A1, lda1);
  initB(W1, wld1);
  stage(0);

  const int rb = l & 15;
  const int koff = ((((l >> 4) + ((l & 15) >> 1)) & 3) * 8);
  int cur = 0;
  for (int ch = 0; ch < nt; ++ch) {
    __syncthreads();
    if (ch + 1 < nt) {
      if (A2 && ch + 1 == nch1) { initA(A2, lda2); initB(W2, wld2); }
      stage(cur ^ 1);
    }
    const u16* Ab = As[cur];
    const u16* Bb = Bs[cur];
    bf16x8 af[4];
#pragma unroll
    for (int rf = 0; rf < 4; ++rf)
      af[rf] = *(const bf16x8*)&Ab[(rf * 16 + rb) * 32 + koff];
#pragma unroll
    for (int g = 0; g < NG; ++g) {
      bf16x8 bfr = *(const bf16x8*)&Bb[(g * 64 + w * 16 + rb) * 32 + koff];
#pragma unroll
      for (int rf = 0; rf < 4; ++rf)
        acc[rf][g] = __builtin_amdgcn_mfma_f32_16x16x32_bf16(af[rf], bfr, acc[rf][g], 0, 0, 0);
    }
    cur ^= 1;
  }

  if constexpr (EPI == 0) {
#pragma unroll
    for (int g = 0; g < NG; ++g) {
      const int wrow = g * gs + yb * ys + w * 16 + colb;
#pragma unroll
      for (int rf = 0; rf < 4; ++rf) {
#pragma unroll
        for (int r = 0; r < 4; ++r) {
          float vv = acc[rf][g][r];
          if (relu) vv = fmaxf(vv, 0.f);
          out0[(bm + rf * 16 + rq * 4 + r) * (long)ldo + wrow] = f2b(vv);
        }
      }
    }
  } else {
    const int cb = yb * ys + w * 16 + colb;
#pragma unroll
    for (int rf = 0; rf < 4; ++rf) {
#pragma unroll
      for (int r = 0; r < 4; ++r) {
        const long row = bm + rf * 16 + rq * 4 + r;
        const float zi = acc[rf][0][r];
        const float zf = acc[rf][1][r];
        const float zg = acc[rf][2][r];
        const float zo = acc[rf][3][r];
        const float cp = cprev ? cprev[row * 256 + cb] : 0.f;
        const float cn = sigf(zf) * cp + sigf(zi) * tanh_f(zg);
        const float hn = sigf(zo) * tanh_f(cn);
        cout[row * 256 + cb] = cn;
        hout[row * (long)ldh + cb] = f2b(hn);
      }
    }
  }
}

// ---------------- fused q-GEMM + attention ----------------
__global__ __launch_bounds__(256, 2)
void qattn_kernel(const u16* __restrict__ A1, long lda1,
                  const u16* __restrict__ W1, int wld1,
                  const float* __restrict__ bias,
                  const u16* __restrict__ ep, const u16* __restrict__ eo,
                  const float* __restrict__ va, const float* __restrict__ ba,
                  u16* __restrict__ dec_in)
{
  __shared__ u16 As[2][64 * 32];
  __shared__ u16 Bs[2][4 * 64 * 32];
  __shared__ u16 qs[64 * 260];
  const int tid = threadIdx.x;
  const int l = tid & 63, w = tid >> 6;
  const long bm = (long)blockIdx.x * 64;
  const int nt = 8;

  const int colb = l & 15, rq = l >> 4;

  f32x4 acc[4][4];
  {
    float bw[4];
#pragma unroll
    for (int g = 0; g < 4; ++g) bw[g] = bias[g * 64 + w * 16 + colb];
#pragma unroll
    for (int rf = 0; rf < 4; ++rf)
#pragma unroll
      for (int g = 0; g < 4; ++g) acc[rf][g] = (f32x4){bw[g], bw[g], bw[g], bw[g]};
  }

  const int l4q = l >> 2;
  const int swzs = (((l & 3) - (l >> 3)) & 3) * 16;

  const char* pA = (const char*)A1 + ((bm + w * 16 + l4q) * lda1) * 2 + swzs;
  const char* pB[4];
#pragma unroll
  for (int c = 0; c < 4; ++c) {
    const int brow = (w * 4 + c) * 16 + l4q;
    pB[c] = (const char*)W1 + ((long)brow * wld1) * 2 + swzs;
  }
  auto stage = [&](int buf) {
    gload16(pA, &As[buf][(w * 16) * 32]);
    pA += 64;
#pragma unroll
    for (int c = 0; c < 4; ++c) {
      gload16(pB[c], &Bs[buf][((w * 4 + c) * 16) * 32]);
      pB[c] += 64;
    }
  };

  stage(0);
  const int rb = l & 15;
  const int koff = ((((l >> 4) + ((l & 15) >> 1)) & 3) * 8);
  int cur = 0;
  for (int ch = 0; ch < nt; ++ch) {
    __syncthreads();
    if (ch + 1 < nt) stage(cur ^ 1);
    const u16* Ab = As[cur];
    const u16* Bb = Bs[cur];
    bf16x8 af[4];
#pragma unroll
    for (int rf = 0; rf < 4; ++rf)
      af[rf] = *(const bf16x8*)&Ab[(rf * 16 + rb) * 32 + koff];
#pragma unroll
    for (int g = 0; g < 4; ++g) {
      bf16x8 bfr = *(const bf16x8*)&Bb[(g * 64 + w * 16 + rb) * 32 + koff];
#pragma unroll
      for (int rf = 0; rf < 4; ++rf)
        acc[rf][g] = __builtin_amdgcn_mfma_f32_16x16x32_bf16(af[rf], bfr, acc[rf][g], 0, 0, 0);
    }
    cur ^= 1;
  }

#pragma unroll
  for (int g = 0; g < 4; ++g) {
    const int col = g * 64 + w * 16 + colb;
#pragma unroll
    for (int rf = 0; rf < 4; ++rf)
#pragma unroll
      for (int r = 0; r < 4; ++r)
        qs[(rf * 16 + rq * 4 + r) * 260 + col] = f2b(acc[rf][g][r]);
  }
  __syncthreads();

  const float ba0 = ba[0];
  const int c = l * 4;
  float vav[4];
  {
    float4 vv = *(const float4*)&va[c];
    vav[0] = vv.x; vav[1] = vv.y; vav[2] = vv.z; vav[3] = vv.w;
  }
  for (int rr = 0; rr < 16; ++rr) {
    const int lrow = w * 16 + rr;
    const long row = bm + lrow;
    float qv[4];
    {
      ushort4 qu = *(const ushort4*)&qs[lrow * 260 + c];
      qv[0] = b2f(qu.x); qv[1] = b2f(qu.y); qv[2] = b2f(qu.z); qv[3] = b2f(qu.w);
    }
    float s[3];
#pragma unroll
    for (int t = 0; t < 3; ++t) {
      ushort4 eu = *(const ushort4*)&ep[row * 768 + t * 256 + c];
      float p = tanh_f(qv[0] + b2f(eu.x)) * vav[0]
              + tanh_f(qv[1] + b2f(eu.y)) * vav[1]
              + tanh_f(qv[2] + b2f(eu.z)) * vav[2]
              + tanh_f(qv[3] + b2f(eu.w)) * vav[3];
#pragma unroll
      for (int m = 32; m; m >>= 1) p += __shfl_xor(p, m);
      s[t] = p + ba0;
    }
    const float mx = fmaxf(s[0], fmaxf(s[1], s[2]));
    const float e0 = __expf(s[0] - mx), e1 = __expf(s[1] - mx), e2 = __expf(s[2] - mx);
    const float inv = rcpf(e0 + e1 + e2);
    const float w0 = e0 * inv, w1 = e1 * inv, w2 = e2 * inv;
    const ushort4 a0 = *(const ushort4*)&eo[row * 768 + 0 * 256 + c];
    const ushort4 a1 = *(const ushort4*)&eo[row * 768 + 1 * 256 + c];
    const ushort4 a2 = *(const ushort4*)&eo[row * 768 + 2 * 256 + c];
    u16* dp = &dec_in[row * 416 + 6 + c];
    dp[0] = f2b(w0 * b2f(a0.x) + w1 * b2f(a1.x) + w2 * b2f(a2.x));
    dp[1] = f2b(w0 * b2f(a0.y) + w1 * b2f(a1.y) + w2 * b2f(a2.y));
    dp[2] = f2b(w0 * b2f(a0.z) + w1 * b2f(a1.z) + w2 * b2f(a2.z));
    dp[3] = f2b(w0 * b2f(a0.w) + w1 * b2f(a1.w) + w2 * b2f(a2.w));
  }
}

// ---------------- fused t1-GEMM + delta ----------------
__global__ __launch_bounds__(256, 2)
void t1delta_kernel(const u16* __restrict__ A1, long lda1,
                    const u16* __restrict__ W1, int wld1,
                    const float* __restrict__ bias,
                    const float* __restrict__ Wo2, const float* __restrict__ bo2,
                    const float* __restrict__ lastp, int lstride,
                    float* __restrict__ outp, int ostride,
                    u16* __restrict__ dec_in)
{
  __shared__ u16 As[2][64 * 32];
  __shared__ u16 Bs[2][2 * 64 * 32];
  __shared__ u16 t1s[64 * 136];
  __shared__ float w2s[768];
  __shared__ float part[64][4][6];
  const int tid = threadIdx.x;
  const int l = tid & 63, w = tid >> 6;
  const long bm = (long)blockIdx.x * 64;
  const int nt = 8;

  for (int i = tid; i < 768; i += 256) w2s[i] = Wo2[i];

  const int colb = l & 15, rq = l >> 4;

  f32x4 acc[4][2];
  {
    float bw[2];
#pragma unroll
    for (int g = 0; g < 2; ++g) bw[g] = bias[g * 64 + w * 16 + colb];
#pragma unroll
    for (int rf = 0; rf < 4; ++rf)
#pragma unroll
      for (int g = 0; g < 2; ++g) acc[rf][g] = (f32x4){bw[g], bw[g], bw[g], bw[g]};
  }

  const int l4q = l >> 2;
  const int swzs = (((l & 3) - (l >> 3)) & 3) * 16;

  const char* pA = (const char*)A1 + ((bm + w * 16 + l4q) * lda1) * 2 + swzs;
  const char* pB[2];
#pragma unroll
  for (int c = 0; c < 2; ++c) {
    const int brow = (w * 2 + c) * 16 + l4q;
    pB[c] = (const char*)W1 + ((long)brow * wld1) * 2 + swzs;
  }
  auto stage = [&](int buf) {
    gload16(pA, &As[buf][(w * 16) * 32]);
    pA += 64;
#pragma unroll
    for (int c = 0; c < 2; ++c) {
      gload16(pB[c], &Bs[buf][((w * 2 + c) * 16) * 32]);
      pB[c] += 64;
    }
  };

  stage(0);
  const int rb = l & 15;
  const int koff = ((((l >> 4) + ((l & 15) >> 1)) & 3) * 8);
  int cur = 0;
  for (int ch = 0; ch < nt; ++ch) {
    __syncthreads();
    if (ch + 1 < nt) stage(cur ^ 1);
    const u16* Ab = As[cur];
    const u16* Bb = Bs[cur];
    bf16x8 af[4];
#pragma unroll
    for (int rf = 0; rf < 4; ++rf)
      af[rf] = *(const bf16x8*)&Ab[(rf * 16 + rb) * 32 + koff];
#pragma unroll
    for (int g = 0; g < 2; ++g) {
      bf16x8 bfr = *(const bf16x8*)&Bb[(g * 64 + w * 16 + rb) * 32 + koff];
#pragma unroll
      for (int rf = 0; rf < 4; ++rf)
        acc[rf][g] = __builtin_amdgcn_mfma_f32_16x16x32_bf16(af[rf], bfr, acc[rf][g], 0, 0, 0);
    }
    cur ^= 1;
  }

#pragma unroll
  for (int g = 0; g < 2; ++g) {
    const int col = g * 64 + w * 16 + colb;
#pragma unroll
    for (int rf = 0; rf < 4; ++rf)
#pragma unroll
      for (int r = 0; r < 4; ++r)
        t1s[(rf * 16 + rq * 4 + r) * 136 + col] = f2b(fmaxf(acc[rf][g][r], 0.f));
  }
  __syncthreads();

  const int rw = tid >> 2, q = tid & 3;
  float p[6] = {0.f, 0.f, 0.f, 0.f, 0.f, 0.f};
  const u16* tp = &t1s[rw * 136 + q * 32];
#pragma unroll
  for (int it = 0; it < 4; ++it) {
    int4 chunk = *(const int4*)&tp[it * 8];
    const u16* cu = (const u16*)&chunk;
#pragma unroll
    for (int e = 0; e < 8; ++e) {
      const float tv = b2f(cu[e]);
      const int k = q * 32 + it * 8 + e;
#pragma unroll
      for (int j = 0; j < 6; ++j) p[j] += tv * w2s[j * 128 + k];
    }
  }
#pragma unroll
  for (int j = 0; j < 6; ++j) part[rw][q][j] = p[j];
  __syncthreads();
  if (tid < 64) {
    const long r2 = bm + tid;
#pragma unroll
    for (int j = 0; j < 6; ++j) {
      const float d = bo2[j] + part[tid][0][j] + part[tid][1][j] + part[tid][2][j] + part[tid][3][j];
      const float pr = lastp[r2 * lstride + j] + d;
      outp[r2 * ostride + j] = pr;
      dec_in[r2 * 416 + j] = f2b(pr);
    }
  }
}

// ---------------- fused front ----------------
__global__ __launch_bounds__(256)
void front_kernel(const float* __restrict__ cbc, const float* __restrict__ baseline,
                  const float* __restrict__ Wb, const float* __restrict__ bb,
                  const float* __restrict__ ln_g, const float* __restrict__ ln_b,
                  u16* __restrict__ dec_in, u16* __restrict__ xbf)
{
  __shared__ float wbs[1280];
  __shared__ float bbs[128], lgs[128], lbs[128];
  const int tid = threadIdx.x;
  for (int i = tid; i < 1280; i += 256) wbs[i] = Wb[i];
  if (tid < 128) { bbs[tid] = bb[tid]; lgs[tid] = ln_g[tid]; lbs[tid] = ln_b[tid]; }
  __syncthreads();
  const int l = tid & 63, w = tid >> 6;
  const long row = (long)blockIdx.x * 4 + w;
#pragma unroll
  for (int e = l; e < 96; e += 64) {
    const int t = e >> 5, c = e & 31;
    xbf[(row * 3 + t) * 32 + c] = (c < 6) ? f2b(cbc[row * 18 + t * 6 + c]) : (u16)0;
  }
  if (l < 6) dec_in[row * 416 + l] = f2b(cbc[row * 18 + 12 + l]);
  else if (l < 32) dec_in[row * 416 + 390 + (l - 6)] = 0;
  float bl[10];
#pragma unroll
  for (int k = 0; k < 10; ++k) bl[k] = baseline[row * 10 + k];
  const int c0 = l, c1 = l + 64;
  float z0 = bbs[c0], z1 = bbs[c1];
#pragma unroll
  for (int k = 0; k < 10; ++k) { z0 += bl[k] * wbs[c0 * 10 + k]; z1 += bl[k] * wbs[c1 * 10 + k]; }
  z0 = fmaxf(z0, 0.f); z1 = fmaxf(z1, 0.f);
  float s = z0 + z1, sq = z0 * z0 + z1 * z1;
#pragma unroll
  for (int m = 32; m; m >>= 1) { s += __shfl_xor(s, m); sq += __shfl_xor(sq, m); }
  const float mu = s * (1.f / 128.f);
  const float var = sq * (1.f / 128.f) - mu * mu;
  const float rs = rsqrtf(var + 1e-5f);
  dec_in[row * 416 + 262 + c0] = f2b((z0 - mu) * rs * lgs[c0] + lbs[c0]);
  dec_in[row * 416 + 262 + c1] = f2b((z1 - mu) * rs * lgs[c1] + lbs[c1]);
}

extern "C" void kernel_launch(void* const* d_in, const int* in_sizes, int n_in,
                              void* d_out, int out_size, void* d_ws, size_t ws_size,
                              hipStream_t stream) {
  const float* cbc   = (const float*)d_in[0];
  const float* base  = (const float*)d_in[1];
  const float* W_ih0 = (const float*)d_in[2];
  const float* W_hh0 = (const float*)d_in[3];
  const float* b_ih0 = (const float*)d_in[4];
  const float* b_hh0 = (const float*)d_in[5];
  const float* W_ih1 = (const float*)d_in[6];
  const float* W_hh1 = (const float*)d_in[7];
  const float* b_ih1 = (const float*)d_in[8];
  const float* b_hh1 = (const float*)d_in[9];
  const float* Wb    = (const float*)d_in[10];
  const float* bb    = (const float*)d_in[11];
  const float* ln_g  = (const float*)d_in[12];
  const float* ln_b  = (const float*)d_in[13];
  const float* W1a   = (const float*)d_in[14];
  const float* b1a   = (const float*)d_in[15];
  const float* W2a   = (const float*)d_in[16];
  const float* b2a   = (const float*)d_in[17];
  const float* va    = (const float*)d_in[18];
  const float* ba    = (const float*)d_in[19];
  const float* Wd_ih = (const float*)d_in[20];
  const float* Wd_hh = (const float*)d_in[21];
  const float* bd_ih = (const float*)d_in[22];
  const float* bd_hh = (const float*)d_in[23];
  const float* Wo1   = (const float*)d_in[24];
  const float* bo1   = (const float*)d_in[25];
  const float* Wo2   = (const float*)d_in[26];
  const float* bo2   = (const float*)d_in[27];
  float* out = (float*)d_out;
  (void)in_sizes; (void)n_in; (void)out_size;

  unsigned char* wsb = (unsigned char*)d_ws;
  size_t off = 0;
  auto alloc = [&](size_t bytes) -> void* {
    void* p = wsb + off;
    off += (bytes + 255) & ~(size_t)255;
    return p;
  };
  u16* wih0b = (u16*)alloc(1024 * 32 * 2);
  u16* whh0b = (u16*)alloc(1024 * 256 * 2);
  u16* wih1b = (u16*)alloc(1024 * 256 * 2);
  u16* whh1b = (u16*)alloc(1024 * 256 * 2);
  u16* wdihb = (u16*)alloc(1024 * 416 * 2);
  u16* wdhhb = (u16*)alloc(1024 * 256 * 2);
  u16* w1ab  = (u16*)alloc(256 * 256 * 2);
  u16* w2ab  = (u16*)alloc(256 * 256 * 2);
  u16* wo1b  = (u16*)alloc(128 * 256 * 2);
  float* bsum0 = (float*)alloc(1024 * 4);
  float* bsum1 = (float*)alloc(1024 * 4);
  float* bsumd = (float*)alloc(1024 * 4);

  // R multiple of 1024 (cell grid (R/128)*4 needs (R/128)%8==0)
  const long perRow = 6656;
  long avail = (long)ws_size - (long)off - 32768;
  long R = avail > 0 ? avail / perRow : 1024;
  R &= ~1023L;
  if (R > BATCH) R = BATCH;
  if (R < 1024) R = 1024;

  u16* xbf    = (u16*)alloc((size_t)R * 96 * 2);
  u16* y0     = (u16*)alloc((size_t)R * 768 * 2);
  u16* y1     = (u16*)alloc((size_t)R * 768 * 2);
  float* cbuf = (float*)alloc((size_t)R * 256 * 4);
  u16* hdec0  = (u16*)alloc((size_t)R * 256 * 2);
  u16* hdec1  = (u16*)alloc((size_t)R * 256 * 2);
  u16* dec_in = (u16*)alloc((size_t)R * 416 * 2);

  {
    PrepP p;
    const float* ss[9] = {W_ih0, W_hh0, W_ih1, W_hh1, Wd_ih, Wd_hh, W1a, W2a, Wo1};
    u16* dd[9]         = {wih0b, whh0b, wih1b, whh1b, wdihb, wdhhb, w1ab, w2ab, wo1b};
    int scv[9]         = {6, 256, 256, 256, 390, 256, 256, 256, 256};
    int dcv[9]         = {32, 256, 256, 256, 416, 256, 256, 256, 256};
    long rows[9]       = {1024, 1024, 1024, 1024, 1024, 1024, 256, 256, 128};
    long cvtTotal = 0;
    for (int i = 0; i < 9; ++i) {
      p.s[i] = ss[i]; p.d[i] = dd[i]; p.sc[i] = scv[i]; p.dc[i] = dcv[i];
      p.n[i] = rows[i] * dcv[i]; cvtTotal += p.n[i];
    }
    p.ba[0] = b_ih0; p.bb_[0] = b_hh0; p.bo[0] = bsum0;
    p.ba[1] = b_ih1; p.bb_[1] = b_hh1; p.bo[1] = bsum1;
    p.ba[2] = bd_ih; p.bb_[2] = bd_hh; p.bo[2] = bsumd;
    prep_kernel<<<dim3(2048), dim3(256), 0, stream>>>(p, cvtTotal, cvtTotal + 3072);
  }

  const dim3 blk(256);

  for (long r0 = 0; r0 < BATCH; r0 += R) {
    const long Rc = (BATCH - r0 < R) ? (BATCH - r0) : R;
    const unsigned nb64 = (unsigned)(Rc / 64);
    const unsigned nb128 = (unsigned)(Rc / 128);
    const dim3 gcell(nb128 * 4);
    const float* cbc_c  = cbc + r0 * 18;
    const float* base_c = base + r0 * 10;
    float* out_c = out + r0 * 30;

    front_kernel<<<dim3((unsigned)(Rc / 4)), blk, 0, stream>>>(
        cbc_c, base_c, Wb, bb, ln_g, ln_b, dec_in, xbf);

    // ---- encoder layer 0 ----
    for (int t = 0; t < 3; ++t) {
      const u16* a2 = t ? (y0 + (t - 1) * 256) : nullptr;
      cell_gemm<<<gcell, blk, 0, stream>>>(
          xbf + t * 32, 96, 32, wih0b, 32,
          a2, 768, 256, whh0b, 256,
          bsum0,
          (t ? cbuf : nullptr), cbuf, y0 + t * 256, 768);
    }
    // ---- encoder layer 1 ----
    for (int t = 0; t < 3; ++t) {
      const u16* a2 = t ? (y1 + (t - 1) * 256) : nullptr;
      cell_gemm<<<gcell, blk, 0, stream>>>(
          y0 + t * 256, 768, 256, wih1b, 256,
          a2, 768, 256, whh1b, 256,
          bsum1,
          (t ? cbuf : nullptr), cbuf, y1 + t * 256, 768);
    }
    // ---- enc_proj (old kernel) ----
    mfma_gemm7<0, 4, 0, 3><<<dim3(nb64 * 3, 1), blk, 0, stream>>>(
        y1, 256, 256, w2ab, 256,
        nullptr, 0, 0, nullptr, 0,
        64, 0, b2a,
        y0, 256, 0,
        nullptr, nullptr, nullptr, 0);

    // ---- decoder ----
    const u16* hcur = y1 + 2 * 256; long hld = 768;
    for (int s = 0; s < 5; ++s) {
      qattn_kernel<<<dim3(nb64), blk, 0, stream>>>(
          hcur, hld, w1ab, 256, b1a, y0, y1, va, ba, dec_in);
      u16* hnext = (s & 1) ? hdec1 : hdec0;
      cell_gemm<<<gcell, blk, 0, stream>>>(
          dec_in, 416, 416, wdihb, 416,
          hcur, hld, 256, wdhhb, 256,
          bsumd,
          cbuf, cbuf, hnext, 256);
      hcur = hnext; hld = 256;
      const float* lastp = (s == 0) ? (cbc_c + 12) : (out_c + (long)(s - 1) * 6);
      const int lstr = (s == 0) ? 18 : 30;
      t1delta_kernel<<<dim3(nb64), blk, 0, stream>>>(
          hcur, 256, wo1b, 256, bo1,
          Wo2, bo2, lastp, lstr, out_c + (long)s * 6, 30, dec_in);
    }
  }
}